// Round 12
// baseline (3233.215 us; speedup 1.0000x reference)
//
#include <hip/hip_runtime.h>
#include <math.h>

#define SEQ 4096
#define BATCH 8
#define NIN 1024
#define NH 256
#define NOUT 128
#define M (SEQ*BATCH)   // 32768

// ---------------- K1: xp = x @ W_xh + b_i2h  (M x NIN) @ (NIN x NH) ----------------
__global__ __launch_bounds__(256) void k_xproj(const float* __restrict__ x,
                                               const float* __restrict__ Wi2h,
                                               const float* __restrict__ bi2h,
                                               float* __restrict__ xp) {
    __shared__ __align__(16) float At[32][64];
    __shared__ __align__(16) float Bt[32][64];
    int bid = blockIdx.x;
    int bn_blk = bid & 3, bm_blk = bid >> 2;
    int m0 = bm_blk * 64, n0 = bn_blk * 64;
    int tid = threadIdx.x;
    int tx = tid & 15, ty = tid >> 4;
    int lr = tid >> 3;
    int lc = tid & 7;
    int bk = tid >> 4;
    int bn = (tid & 15) * 4;

    float acc[4][4];
    #pragma unroll
    for (int i = 0; i < 4; i++)
        #pragma unroll
        for (int j = 0; j < 4; j++) acc[i][j] = 0.f;

    for (int k0 = 0; k0 < NIN; k0 += 32) {
        float4 a0 = *(const float4*)&x[(size_t)(m0 + lr)      * NIN + k0 + lc * 4];
        float4 a1 = *(const float4*)&x[(size_t)(m0 + lr + 32) * NIN + k0 + lc * 4];
        float4 b0 = *(const float4*)&Wi2h[(size_t)(k0 + bk)      * NH + n0 + bn];
        float4 b1 = *(const float4*)&Wi2h[(size_t)(k0 + bk + 16) * NH + n0 + bn];
        __syncthreads();
        At[lc*4+0][lr] = a0.x; At[lc*4+1][lr] = a0.y; At[lc*4+2][lr] = a0.z; At[lc*4+3][lr] = a0.w;
        At[lc*4+0][lr+32] = a1.x; At[lc*4+1][lr+32] = a1.y; At[lc*4+2][lr+32] = a1.z; At[lc*4+3][lr+32] = a1.w;
        *(float4*)&Bt[bk][bn]      = b0;
        *(float4*)&Bt[bk+16][bn]   = b1;
        __syncthreads();
        #pragma unroll
        for (int kk = 0; kk < 32; kk++) {
            float4 av = *(const float4*)&At[kk][ty*4];
            float4 bv = *(const float4*)&Bt[kk][tx*4];
            float a[4] = {av.x, av.y, av.z, av.w};
            float b[4] = {bv.x, bv.y, bv.z, bv.w};
            #pragma unroll
            for (int i = 0; i < 4; i++)
                #pragma unroll
                for (int j = 0; j < 4; j++)
                    acc[i][j] = fmaf(a[i], b[j], acc[i][j]);
        }
    }
    float4 bb = *(const float4*)&bi2h[n0 + tx*4];
    float bias[4] = {bb.x, bb.y, bb.z, bb.w};
    #pragma unroll
    for (int i = 0; i < 4; i++) {
        float4 v = make_float4(acc[i][0] + bias[0], acc[i][1] + bias[1],
                               acc[i][2] + bias[2], acc[i][3] + bias[3]);
        *(float4*)&xp[(size_t)(m0 + ty*4 + i) * NH + n0 + tx*4] = v;
    }
}

// ---------------- K2: sequential scan, one block per batch ----------------
// 1024 threads = 16 waves. Thread (cb = tid>>4, kb = tid&15):
//   owns 4 cols (4cb..4cb+3) x 16 k-rows (16kb..16kb+15) -> 64 f32 weights.
// WHY (R10 evidence): gfx950 VALU cannot read AGPR sources (assembler rejects
// v_fma_f32 with 'a' operand), so any AGPR-parked weight costs a per-use
// v_accvgpr_read. 128 w/thread never stayed in arch VGPRs (R4-R9, stuck at
// 84-92 + copies). 64 w/thread + waves_per_eu(4,4) (budget 128) fits ~112.
// Reduction over 16 kb lanes moved OFF the LDS pipe: DPP adds on VALU
// (quad_perm xor1/xor2, shl4/shr4+select for xor4, shl8+shr8 bound_ctrl=0
// for xor8). LDS per step: 4x ds_read_b128 + 1 write per thread, no shuffles.
// Lane ends owning col 4cb + (kb&3); kb>>2==0 writes LDS h, ==1 writes hs.
// ONE lgkm-only barrier per step; hs store + xp prefetch stay in flight.
template <int CTRL>
__device__ __forceinline__ float dppf(float x) {
    int r = __builtin_amdgcn_update_dpp(0, __builtin_bit_cast(int, x),
                                        CTRL, 0xF, 0xF, true);
    return __builtin_bit_cast(float, r);
}

__global__ __launch_bounds__(1024) __attribute__((amdgpu_waves_per_eu(4, 4)))
void k_scan(const float* __restrict__ Wi2h,
            const float* __restrict__ h0,
            const float* __restrict__ xp,
            float* __restrict__ hs) {
    __shared__ __align__(16) float hbuf[2][NH];
    int b = blockIdx.x;
    int tid = threadIdx.x;
    int cb = tid >> 4;            // 0..63 -> columns 4cb..4cb+3
    int kb = tid & 15;            // 0..15 -> k rows 16kb..16kb+15
    int colf = 4*cb + (kb & 3);   // owned column after reduce

    // Weights: w4[c][q] = W_hh[16kb + 4*((q+kb)&3) + e][4cb+c], e=0..3
    float4 w4[4][4];
    #pragma unroll
    for (int c = 0; c < 4; c++) {
        #pragma unroll
        for (int q = 0; q < 4; q++) {
            int kk = 16*kb + 4*((q + kb) & 3);
            const float* base = &Wi2h[(size_t)(NIN + kk) * NH + 4*cb + c];
            w4[c][q].x = base[0*NH];
            w4[c][q].y = base[1*NH];
            w4[c][q].z = base[2*NH];
            w4[c][q].w = base[3*NH];
        }
    }
    // Launder (prevent remat; values opaque)
    #pragma unroll
    for (int c = 0; c < 4; c++)
        #pragma unroll
        for (int q = 0; q < 4; q++)
            asm volatile("" : "+v"(w4[c][q].x), "+v"(w4[c][q].y),
                             "+v"(w4[c][q].z), "+v"(w4[c][q].w));

    if (tid < NH) hbuf[0][tid] = h0[b*NH + tid];
    float xc = xp[(size_t)(0*BATCH + b) * NH + colf];
    __syncthreads();

    for (int t = 0; t < SEQ; t++) {
        const float* rb = &hbuf[t & 1][16 * kb];
        float xn = 0.f;
        if (t + 1 < SEQ) xn = xp[(size_t)((t+1)*BATCH + b) * NH + colf];

        float4 hv[4];
        #pragma unroll
        for (int q = 0; q < 4; q++)
            hv[q] = *(const float4*)&rb[4 * ((q + kb) & 3)];

        float a0 = 0.f, a1 = 0.f, a2 = 0.f, a3 = 0.f;
        #pragma unroll
        for (int q = 0; q < 4; q++) {
            a0 = fmaf(hv[q].x, w4[0][q].x, a0); a0 = fmaf(hv[q].y, w4[0][q].y, a0);
            a0 = fmaf(hv[q].z, w4[0][q].z, a0); a0 = fmaf(hv[q].w, w4[0][q].w, a0);
            a1 = fmaf(hv[q].x, w4[1][q].x, a1); a1 = fmaf(hv[q].y, w4[1][q].y, a1);
            a1 = fmaf(hv[q].z, w4[1][q].z, a1); a1 = fmaf(hv[q].w, w4[1][q].w, a1);
            a2 = fmaf(hv[q].x, w4[2][q].x, a2); a2 = fmaf(hv[q].y, w4[2][q].y, a2);
            a2 = fmaf(hv[q].z, w4[2][q].z, a2); a2 = fmaf(hv[q].w, w4[2][q].w, a2);
            a3 = fmaf(hv[q].x, w4[3][q].x, a3); a3 = fmaf(hv[q].y, w4[3][q].y, a3);
            a3 = fmaf(hv[q].z, w4[3][q].z, a3); a3 = fmaf(hv[q].w, w4[3][q].w, a3);
        }

        // ---- DPP reduction over 16 kb-lanes (VALU pipe, no LDS) ----
        bool s0 = (kb & 1) != 0, s1 = (kb & 2) != 0;
        float u  = s0 ? a1 : a0, du = s0 ? a0 : a1;
        float v  = s0 ? a3 : a2, dv = s0 ? a2 : a3;
        u += dppf<0xB1>(du);                    // quad_perm(1,0,3,2): xor1
        v += dppf<0xB1>(dv);
        float w  = s1 ? v : u,  dw = s1 ? u : v;
        w += dppf<0x4E>(dw);                    // quad_perm(2,3,0,1): xor2
        float p4a = dppf<0x104>(w);             // row_shl:4
        float p4b = dppf<0x114>(w);             // row_shr:4
        w += (kb & 4) ? p4b : p4a;              // xor4
        w += dppf<0x108>(w) + dppf<0x118>(w);   // xor8: shl8 + shr8 (bound_ctrl zeros)

        float s = w + xc;
        // tanh via (z-1)/(z+1), z = exp2(2*log2(e)*s)
        float arg = s * 2.88539004f;
        float z;
        asm("v_exp_f32 %0, %1" : "=v"(z) : "v"(arg));
        float inv;
        float den = z + 1.0f;
        asm("v_rcp_f32 %0, %1" : "=v"(inv) : "v"(den));
        float hn = (z - 1.0f) * inv;

        int role = kb >> 2;
        if (role == 0) hbuf[(t + 1) & 1][colf] = hn;                    // LDS for next step
        else if (role == 1) hs[(size_t)(t*BATCH + b) * NH + colf] = hn; // global, in flight
        xc = xn;

        asm volatile("s_waitcnt lgkmcnt(0)" ::: "memory");
        __builtin_amdgcn_s_barrier();
        asm volatile("" ::: "memory");
    }
}

// ---------------- K3: out = hs @ W_h2o + b_h2o ----------------
__global__ __launch_bounds__(256) void k_out(const float* __restrict__ hs,
                                             const float* __restrict__ Wh2o,
                                             const float* __restrict__ bh2o,
                                             float* __restrict__ out) {
    __shared__ float Wl[NH][64];
    __shared__ float Hl[8][NH];
    int bid = blockIdx.x;
    int half = bid & 1;
    int rt = bid >> 1;
    int tid = threadIdx.x;

    for (int i = tid; i < NH*64; i += 256) {
        int k = i >> 6, o = i & 63;
        Wl[k][o] = Wh2o[(size_t)k*NOUT + half*64 + o];
    }
    int o = tid & 63, g = tid >> 6;
    float bias = bh2o[half*64 + o];

    for (int tile = 0; tile < 16; tile++) {
        int r0 = rt*128 + tile*8;
        __syncthreads();
        for (int i = tid; i < 8*NH; i += 256)
            Hl[i >> 8][i & 255] = hs[(size_t)r0*NH + i];
        __syncthreads();
        float a0 = 0.f, a1 = 0.f;
        int r = g * 2;
        #pragma unroll 8
        for (int k = 0; k < NH; k++) {
            float wv = Wl[k][o];
            a0 = fmaf(Hl[r][k],   wv, a0);
            a1 = fmaf(Hl[r+1][k], wv, a1);
        }
        out[(size_t)(r0 + r)     * NOUT + half*64 + o] = a0 + bias;
        out[(size_t)(r0 + r + 1) * NOUT + half*64 + o] = a1 + bias;
    }
}

extern "C" void kernel_launch(void* const* d_in, const int* in_sizes, int n_in,
                              void* d_out, int out_size, void* d_ws, size_t ws_size,
                              hipStream_t stream) {
    const float* x    = (const float*)d_in[0];
    const float* h0   = (const float*)d_in[1];
    const float* Wi2h = (const float*)d_in[2];
    const float* bi2h = (const float*)d_in[3];
    const float* Wh2o = (const float*)d_in[4];
    const float* bh2o = (const float*)d_in[5];
    float* out = (float*)d_out;

    float* xp = (float*)d_ws;                     // M*NH f32 = 32 MB
    float* hs = xp + (size_t)M * NH;              // M*NH f32 = 32 MB

    k_xproj<<<dim3(2048), dim3(256),  0, stream>>>(x, Wi2h, bi2h, xp);
    k_scan <<<dim3(BATCH), dim3(1024), 0, stream>>>(Wi2h, h0, xp, hs);
    k_out  <<<dim3(512),  dim3(256),  0, stream>>>(hs, Wh2o, bh2o, out);
}

// Round 13
// 2622.651 us; speedup vs baseline: 1.2328x; 1.2328x over previous
//
#include <hip/hip_runtime.h>
#include <math.h>

#define SEQ 4096
#define BATCH 8
#define NIN 1024
#define NH 256
#define NOUT 128
#define M (SEQ*BATCH)   // 32768

// ---------------- K1: xp = x @ W_xh + b_i2h  (M x NIN) @ (NIN x NH) ----------------
__global__ __launch_bounds__(256) void k_xproj(const float* __restrict__ x,
                                               const float* __restrict__ Wi2h,
                                               const float* __restrict__ bi2h,
                                               float* __restrict__ xp) {
    __shared__ __align__(16) float At[32][64];
    __shared__ __align__(16) float Bt[32][64];
    int bid = blockIdx.x;
    int bn_blk = bid & 3, bm_blk = bid >> 2;
    int m0 = bm_blk * 64, n0 = bn_blk * 64;
    int tid = threadIdx.x;
    int tx = tid & 15, ty = tid >> 4;
    int lr = tid >> 3;
    int lc = tid & 7;
    int bk = tid >> 4;
    int bn = (tid & 15) * 4;

    float acc[4][4];
    #pragma unroll
    for (int i = 0; i < 4; i++)
        #pragma unroll
        for (int j = 0; j < 4; j++) acc[i][j] = 0.f;

    for (int k0 = 0; k0 < NIN; k0 += 32) {
        float4 a0 = *(const float4*)&x[(size_t)(m0 + lr)      * NIN + k0 + lc * 4];
        float4 a1 = *(const float4*)&x[(size_t)(m0 + lr + 32) * NIN + k0 + lc * 4];
        float4 b0 = *(const float4*)&Wi2h[(size_t)(k0 + bk)      * NH + n0 + bn];
        float4 b1 = *(const float4*)&Wi2h[(size_t)(k0 + bk + 16) * NH + n0 + bn];
        __syncthreads();
        At[lc*4+0][lr] = a0.x; At[lc*4+1][lr] = a0.y; At[lc*4+2][lr] = a0.z; At[lc*4+3][lr] = a0.w;
        At[lc*4+0][lr+32] = a1.x; At[lc*4+1][lr+32] = a1.y; At[lc*4+2][lr+32] = a1.z; At[lc*4+3][lr+32] = a1.w;
        *(float4*)&Bt[bk][bn]      = b0;
        *(float4*)&Bt[bk+16][bn]   = b1;
        __syncthreads();
        #pragma unroll
        for (int kk = 0; kk < 32; kk++) {
            float4 av = *(const float4*)&At[kk][ty*4];
            float4 bv = *(const float4*)&Bt[kk][tx*4];
            float a[4] = {av.x, av.y, av.z, av.w};
            float b[4] = {bv.x, bv.y, bv.z, bv.w};
            #pragma unroll
            for (int i = 0; i < 4; i++)
                #pragma unroll
                for (int j = 0; j < 4; j++)
                    acc[i][j] = fmaf(a[i], b[j], acc[i][j]);
        }
    }
    float4 bb = *(const float4*)&bi2h[n0 + tx*4];
    float bias[4] = {bb.x, bb.y, bb.z, bb.w};
    #pragma unroll
    for (int i = 0; i < 4; i++) {
        float4 v = make_float4(acc[i][0] + bias[0], acc[i][1] + bias[1],
                               acc[i][2] + bias[2], acc[i][3] + bias[3]);
        *(float4*)&xp[(size_t)(m0 + ty*4 + i) * NH + n0 + tx*4] = v;
    }
}

// ---------------- K2: sequential scan, one block per batch (R6 base + DPP reduce) ---
// 512 threads = 8 waves. Thread (cb = tid>>3, kb = tid&7) owns 4 cols x 32 k,
// weights laundered "+v" (R6 config, best measured: 2330 us).
// ONLY change vs R6: the reduction over kb lanes (xor1, xor2, xor4) moved from
// __shfl_xor (ds_permute: ~120-cyc LDS round trip each, 3 DEPENDENT = ~360 cyc
// serial per step) to DPP on the VALU pipe (~8 cyc/hop). Evidence: R7 halved
// FMA count + weight regs with NO time change -> scan is latency-bound, not
// issue-bound; the shfl chain is the dominant serial latency.
// kb = lane bits 0-2. xor1 = quad_perm(1,0,3,2)=0xB1, xor2 = quad_perm(2,3,0,1)
// =0x4E (R12-verified). xor4 has no within-8 DPP primitive: compose
// v[i^4] = HalfMirror(QP_xor2(QP_xor1(v)))  (i^1^2^7 = i^4), ctrl 0x141.
// Identical add tree to R6 -> bit-identical result expected.
template <int CTRL>
__device__ __forceinline__ float dppf(float x) {
    int r = __builtin_amdgcn_update_dpp(0, __builtin_bit_cast(int, x),
                                        CTRL, 0xF, 0xF, true);
    return __builtin_bit_cast(float, r);
}

__global__ __launch_bounds__(512) __attribute__((amdgpu_waves_per_eu(2, 2)))
void k_scan(const float* __restrict__ Wi2h,
            const float* __restrict__ h0,
            const float* __restrict__ xp,
            float* __restrict__ hs) {
    __shared__ __align__(16) float hbuf[2][NH];
    int b = blockIdx.x;
    int tid = threadIdx.x;
    int cb = tid >> 3;            // 0..63  -> columns 4cb..4cb+3
    int kb = tid & 7;             // 0..7   -> k rows 32kb..32kb+31
    int b0 = kb & 1, b1 = (kb >> 1) & 1;
    int colf = 4*cb + (b0 << 1) + b1;    // final owned column after reduce

    // Weight registers: w4[c][j] = W_hh[32kb + 4*((j+kb)&7) + e][4cb+c]
    float4 w4[4][8];
    #pragma unroll
    for (int c = 0; c < 4; c++) {
        #pragma unroll
        for (int j = 0; j < 8; j++) {
            int kk = 32*kb + 4*((j + kb) & 7);
            const float* base = &Wi2h[(size_t)(NIN + kk) * NH + 4*cb + c];
            w4[c][j].x = base[0*NH];
            w4[c][j].y = base[1*NH];
            w4[c][j].z = base[2*NH];
            w4[c][j].w = base[3*NH];
        }
    }
    // Launder: opaque asm results -> cannot be rematerialized from global.
    #pragma unroll
    for (int c = 0; c < 4; c++)
        #pragma unroll
        for (int j = 0; j < 8; j++)
            asm volatile("" : "+v"(w4[c][j].x), "+v"(w4[c][j].y),
                             "+v"(w4[c][j].z), "+v"(w4[c][j].w));

    if (tid < NH) hbuf[0][tid] = h0[b*NH + tid];
    float xc = xp[(size_t)(0*BATCH + b) * NH + colf];
    __syncthreads();

    for (int t = 0; t < SEQ; t++) {
        const float* rb = &hbuf[t & 1][32 * kb];
        float xn = 0.f;
        if (t + 1 < SEQ) xn = xp[(size_t)((t+1)*BATCH + b) * NH + colf];

        // load h chunk (bank-staggered) and FMA into 4 column accumulators
        float4 hv[8];
        #pragma unroll
        for (int j = 0; j < 8; j++)
            hv[j] = *(const float4*)&rb[4 * ((j + kb) & 7)];

        float a0 = 0.f, a1 = 0.f, a2 = 0.f, a3 = 0.f;
        #pragma unroll
        for (int j = 0; j < 8; j++) {
            a0 = fmaf(hv[j].x, w4[0][j].x, a0); a0 = fmaf(hv[j].y, w4[0][j].y, a0);
            a0 = fmaf(hv[j].z, w4[0][j].z, a0); a0 = fmaf(hv[j].w, w4[0][j].w, a0);
            a1 = fmaf(hv[j].x, w4[1][j].x, a1); a1 = fmaf(hv[j].y, w4[1][j].y, a1);
            a1 = fmaf(hv[j].z, w4[1][j].z, a1); a1 = fmaf(hv[j].w, w4[1][j].w, a1);
            a2 = fmaf(hv[j].x, w4[2][j].x, a2); a2 = fmaf(hv[j].y, w4[2][j].y, a2);
            a2 = fmaf(hv[j].z, w4[2][j].z, a2); a2 = fmaf(hv[j].w, w4[2][j].w, a2);
            a3 = fmaf(hv[j].x, w4[3][j].x, a3); a3 = fmaf(hv[j].y, w4[3][j].y, a3);
            a3 = fmaf(hv[j].z, w4[3][j].z, a3); a3 = fmaf(hv[j].w, w4[3][j].w, a3);
        }

        // ---- select-fold reduction over kb lanes via DPP (VALU pipe) ----
        bool s0 = (kb & 1) != 0, s1 = (kb & 2) != 0;
        float k0v = s0 ? a2 : a0, k1v = s0 ? a3 : a1;
        float d0  = s0 ? a0 : a2, d1  = s0 ? a1 : a3;
        k0v += dppf<0xB1>(d0);              // + v[lane^1]
        k1v += dppf<0xB1>(d1);
        float ke = s1 ? k1v : k0v;
        float de = s1 ? k0v : k1v;
        ke += dppf<0x4E>(de);               // + v[lane^2]
        // + v[lane^4]: compose xor1 -> xor2 -> half-mirror (xor7): net xor4
        float x1 = dppf<0xB1>(ke);
        float x2 = dppf<0x4E>(x1);
        float x3 = dppf<0x141>(x2);
        ke += x3;

        float s = ke + xc;
        // tanh via (z-1)/(z+1), z = exp2(2*log2(e)*s)
        float arg = s * 2.88539004f;
        float z;
        asm("v_exp_f32 %0, %1" : "=v"(z) : "v"(arg));
        float inv;
        float den = z + 1.0f;
        asm("v_rcp_f32 %0, %1" : "=v"(inv) : "v"(den));
        float hn = (z - 1.0f) * inv;

        if ((kb & 4) == 0) hbuf[(t + 1) & 1][colf] = hn;               // LDS for next step
        else               hs[(size_t)(t*BATCH + b) * NH + colf] = hn; // global, in flight
        xc = xn;

        asm volatile("s_waitcnt lgkmcnt(0)" ::: "memory");
        __builtin_amdgcn_s_barrier();
        asm volatile("" ::: "memory");
    }
}

// ---------------- K3: out = hs @ W_h2o + b_h2o ----------------
__global__ __launch_bounds__(256) void k_out(const float* __restrict__ hs,
                                             const float* __restrict__ Wh2o,
                                             const float* __restrict__ bh2o,
                                             float* __restrict__ out) {
    __shared__ float Wl[NH][64];
    __shared__ float Hl[8][NH];
    int bid = blockIdx.x;
    int half = bid & 1;
    int rt = bid >> 1;
    int tid = threadIdx.x;

    for (int i = tid; i < NH*64; i += 256) {
        int k = i >> 6, o = i & 63;
        Wl[k][o] = Wh2o[(size_t)k*NOUT + half*64 + o];
    }
    int o = tid & 63, g = tid >> 6;
    float bias = bh2o[half*64 + o];

    for (int tile = 0; tile < 16; tile++) {
        int r0 = rt*128 + tile*8;
        __syncthreads();
        for (int i = tid; i < 8*NH; i += 256)
            Hl[i >> 8][i & 255] = hs[(size_t)r0*NH + i];
        __syncthreads();
        float a0 = 0.f, a1 = 0.f;
        int r = g * 2;
        #pragma unroll 8
        for (int k = 0; k < NH; k++) {
            float wv = Wl[k][o];
            a0 = fmaf(Hl[r][k],   wv, a0);
            a1 = fmaf(Hl[r+1][k], wv, a1);
        }
        out[(size_t)(r0 + r)     * NOUT + half*64 + o] = a0 + bias;
        out[(size_t)(r0 + r + 1) * NOUT + half*64 + o] = a1 + bias;
    }
}

extern "C" void kernel_launch(void* const* d_in, const int* in_sizes, int n_in,
                              void* d_out, int out_size, void* d_ws, size_t ws_size,
                              hipStream_t stream) {
    const float* x    = (const float*)d_in[0];
    const float* h0   = (const float*)d_in[1];
    const float* Wi2h = (const float*)d_in[2];
    const float* bi2h = (const float*)d_in[3];
    const float* Wh2o = (const float*)d_in[4];
    const float* bh2o = (const float*)d_in[5];
    float* out = (float*)d_out;

    float* xp = (float*)d_ws;                     // M*NH f32 = 32 MB
    float* hs = xp + (size_t)M * NH;              // M*NH f32 = 32 MB

    k_xproj<<<dim3(2048), dim3(256), 0, stream>>>(x, Wi2h, bi2h, xp);
    k_scan <<<dim3(BATCH), dim3(512), 0, stream>>>(Wi2h, h0, xp, hs);
    k_out  <<<dim3(512), dim3(256), 0, stream>>>(hs, Wh2o, bh2o, out);
}